// Round 1
// baseline (386.474 us; speedup 1.0000x reference)
//
#include <hip/hip_runtime.h>

// Single-layer tanh RNN scan: h_t = tanh(x_t @ W_ih^T + b_ih + b_hh + h_{t-1} @ W_hh^T)
// SEQ=2048, BATCH=4096, IN=3, HID=5.
//
// Design:
//  - One persistent kernel; the 2048-step serial scan runs inside the kernel.
//  - 8 lanes per batch element: lane j (j = tid&7) owns hidden unit min(j,4).
//    Lanes j=5..7 duplicate row 4 (same weights -> same value -> same store
//    address as lane 4: benign duplicate store), so there is NO divergence.
//  - h_{t-1} gathered across the 8-lane group with ds_swizzle (BitMode:
//    and=0x18 keeps group base bits, or=k selects source lane) — one LDS
//    crossbar hop, no vaddr registers, no barriers (same wave).
//  - tanh(a) = 1 - 2/(1+e^{2a}); all weights/biases pre-scaled by 2*log2(e)
//    so e^{2a} = v_exp_f32(a_scaled) directly. rcp via v_rcp_f32.
//  - x is prefetched 16 timesteps ahead into a double-buffered register file
//    (2 x 16 x 3 floats) to cover ~900-cycle HBM miss latency with ~1100
//    cycles of compute per block.

#ifndef __has_builtin
#define __has_builtin(x) 0
#endif

__device__ __forceinline__ float fast_exp2(float x) {
#if __has_builtin(__builtin_amdgcn_exp2f)
  return __builtin_amdgcn_exp2f(x);
#else
  return exp2f(x);
#endif
}

__device__ __forceinline__ float fast_rcp(float x) {
  return __builtin_amdgcn_rcpf(x);
}

constexpr int S  = 2048;
constexpr int B  = 4096;
constexpr int IN = 3;
constexpr int H  = 5;
constexpr int PF = 16;          // timesteps prefetched per block
constexpr int NBLK = S / PF;    // 128

__global__ void __launch_bounds__(64) rnn_scan_kernel(
    const float* __restrict__ x,    // (S, B, IN)
    const float* __restrict__ h0,   // (1, B, H)
    const float* __restrict__ Wih,  // (H, IN)
    const float* __restrict__ Whh,  // (H, H)
    const float* __restrict__ bih,  // (H)
    const float* __restrict__ bhh,  // (H)
    float* __restrict__ out)        // ys (S,B,H) then h_n (1,B,H)
{
  const int tid = blockIdx.x * 64 + threadIdx.x;
  const int b   = tid >> 3;          // batch element [0, 4096)
  const int j   = tid & 7;           // lane within group
  const int jw  = (j < 5) ? j : 4;   // hidden row this lane computes

  // 2*log2(e): fold the tanh input scaling into the weights.
  const float c = 2.885390081777927f;

  const float wi0 = c * Wih[jw * 3 + 0];
  const float wi1 = c * Wih[jw * 3 + 1];
  const float wi2 = c * Wih[jw * 3 + 2];
  const float wh0 = c * Whh[jw * 5 + 0];
  const float wh1 = c * Whh[jw * 5 + 1];
  const float wh2 = c * Whh[jw * 5 + 2];
  const float wh3 = c * Whh[jw * 5 + 3];
  const float wh4 = c * Whh[jw * 5 + 4];
  const float bb  = c * (bih[jw] + bhh[jw]);

  float h = h0[b * H + jw];

  const float* xbase = x + (size_t)b * IN;
  float*       op    = out + (size_t)b * H + jw;

  float xa[PF * 3];
  float xb[PF * 3];

  auto loadblk = [&](float* dst, int blk) {
    const float* p = xbase + (size_t)blk * PF * B * IN;
#pragma unroll
    for (int u = 0; u < PF; ++u) {
      dst[u * 3 + 0] = p[(size_t)u * B * IN + 0];
      dst[u * 3 + 1] = p[(size_t)u * B * IN + 1];
      dst[u * 3 + 2] = p[(size_t)u * B * IN + 2];
    }
  };

  auto compute = [&](const float* xv) {
#pragma unroll
    for (int u = 0; u < PF; ++u) {
      // input projection (independent of h -> overlaps the swizzle latency)
      float xp = fmaf(wi0, xv[u * 3 + 0],
                 fmaf(wi1, xv[u * 3 + 1],
                 fmaf(wi2, xv[u * 3 + 2], bb)));

      // gather h_0..h_4 from lanes (group_base + k) — pull-style broadcast
      float g0 = __int_as_float(__builtin_amdgcn_ds_swizzle(__float_as_int(h), (0 << 5) | 0x18));
      float g1 = __int_as_float(__builtin_amdgcn_ds_swizzle(__float_as_int(h), (1 << 5) | 0x18));
      float g2 = __int_as_float(__builtin_amdgcn_ds_swizzle(__float_as_int(h), (2 << 5) | 0x18));
      float g3 = __int_as_float(__builtin_amdgcn_ds_swizzle(__float_as_int(h), (3 << 5) | 0x18));
      float g4 = __int_as_float(__builtin_amdgcn_ds_swizzle(__float_as_int(h), (4 << 5) | 0x18));

      // scaled pre-activation (tree-shaped for short critical path)
      float a = (g0 * wh0 + g1 * wh1) + (g2 * wh2 + g3 * wh3) + (g4 * wh4 + xp);

      // tanh(a/c) = 1 - 2/(1 + exp2(a))
      float t = fast_exp2(a);
      h = fmaf(-2.0f, fast_rcp(1.0f + t), 1.0f);

      op[(size_t)u * B * H] = h;
    }
    op += (size_t)PF * B * H;
  };

  loadblk(xa, 0);
  for (int blk = 0; blk < NBLK; blk += 2) {
    loadblk(xb, blk + 1);          // in flight while computing xa's block
    compute(xa);
    if (blk + 2 < NBLK) loadblk(xa, blk + 2);
    compute(xb);
  }

  // h_n tail: out[S*B*H + b*H + j]
  out[(size_t)S * B * H + b * H + jw] = h;
}

extern "C" void kernel_launch(void* const* d_in, const int* in_sizes, int n_in,
                              void* d_out, int out_size, void* d_ws, size_t ws_size,
                              hipStream_t stream) {
  const float* x   = (const float*)d_in[0];
  const float* h0  = (const float*)d_in[1];
  const float* Wih = (const float*)d_in[2];
  const float* Whh = (const float*)d_in[3];
  const float* bih = (const float*)d_in[4];
  const float* bhh = (const float*)d_in[5];
  float* out = (float*)d_out;

  // 4096 batch elements * 8 lanes = 32768 threads = 512 blocks of 64.
  dim3 grid((B * 8) / 64), block(64);
  rnn_scan_kernel<<<grid, block, 0, stream>>>(x, h0, Wih, Whh, bih, bhh, out);
}

// Round 2
// 375.748 us; speedup vs baseline: 1.0285x; 1.0285x over previous
//
#include <hip/hip_runtime.h>

// Single-layer tanh RNN scan: h_t = tanh(x_t @ W_ih^T + b_ih + b_hh + h_{t-1} @ W_hh^T)
// SEQ=2048, BATCH=4096, IN=3, HID=5.
//
// Round-2 change: the per-step cross-lane gather of h moved from ds_swizzle
// (LDS pipe, ~120 cyc latency -> ~230 cyc/step measured) to a 3-stage DPP
// butterfly all-gather (VALU pipe, ~6 cyc/stage):
//   stage1: quad_perm[1,0,3,2]  (lane i <- i^1)   1 mov
//   stage2: quad_perm[2,3,0,1]  (lane i <- i^2)   2 movs
//   stage3: row_half_mirror     (lane i <- i^7)   4 movs
// After the butterfly, slot d holds h[group_base + (j^d)] (slots 4..7 hold
// d=7,6,5,4 respectively). Lane-dependent slot->hidden-unit mapping is folded
// into per-lane PERMUTED weights at init:
//   w'_slot = (j ^ d(slot) <= 4) ? c*Whh[jw][j ^ d(slot)] : 0
// so the recurrent matvec is 8 in-lane FMAs; no LDS ops remain in the kernel.
//
// tanh(a) = 1 - 2/(1+e^{2a}); weights/biases pre-scaled by 2*log2(e) so
// e^{2a} = v_exp_f32(a_scaled). Chain/step ~= 8-FMA dot + exp + rcp + fma.

__device__ __forceinline__ float fast_exp2(float x) {
  return __builtin_amdgcn_exp2f(x);
}
__device__ __forceinline__ float fast_rcp(float x) {
  return __builtin_amdgcn_rcpf(x);
}

// DPP cross-lane move: dst[lane] = src[perm(lane)], perm within 16-lane row.
#define DPP_QUAD_XOR1 0xB1   // quad_perm [1,0,3,2]
#define DPP_QUAD_XOR2 0x4E   // quad_perm [2,3,0,1]
#define DPP_ROW_HMIRR 0x141  // row_half_mirror: lane i <- i^7 (within 8)

template <int CTRL>
__device__ __forceinline__ float dpp_mov(float v) {
  return __int_as_float(__builtin_amdgcn_update_dpp(
      0, __float_as_int(v), CTRL, 0xF, 0xF, false));
}

constexpr int S  = 2048;
constexpr int B  = 4096;
constexpr int IN = 3;
constexpr int H  = 5;
constexpr int PF = 16;          // timesteps prefetched per block
constexpr int NBLK = S / PF;    // 128

__global__ void __launch_bounds__(64) rnn_scan_kernel(
    const float* __restrict__ x,    // (S, B, IN)
    const float* __restrict__ h0,   // (1, B, H)
    const float* __restrict__ Wih,  // (H, IN)
    const float* __restrict__ Whh,  // (H, H)
    const float* __restrict__ bih,  // (H)
    const float* __restrict__ bhh,  // (H)
    float* __restrict__ out)        // ys (S,B,H) then h_n (1,B,H)
{
  const int tid = blockIdx.x * 64 + threadIdx.x;
  const int b   = tid >> 3;          // batch element [0, 4096)
  const int j   = tid & 7;           // lane within 8-lane group
  const int jw  = (j < 5) ? j : 4;   // hidden row this lane computes

  // 2*log2(e): fold tanh's input scaling into weights/biases.
  const float c = 2.885390081777927f;

  const float wi0 = c * Wih[jw * 3 + 0];
  const float wi1 = c * Wih[jw * 3 + 1];
  const float wi2 = c * Wih[jw * 3 + 2];
  const float bb  = c * (bih[jw] + bhh[jw]);

  // Butterfly-permuted recurrent weights. Slot s receives h[lane j ^ d(s)]
  // where d(s) = s for s<4, and 11-s for s>=4 (row_half_mirror of slot s-4).
  float wh[8];
#pragma unroll
  for (int s = 0; s < 8; ++s) {
    const int d = (s < 4) ? s : (11 - s);
    const int k = j ^ d;
    wh[s] = (k <= 4) ? c * Whh[jw * 5 + ((k < 5) ? k : 0)] : 0.0f;
  }
  // (k<=4 guard makes the index safe; ternary inside keeps it in-bounds
  //  for the compiler even when wh[s]==0 is selected.)

  float h = h0[b * H + jw];

  const float* xbase = x + (size_t)b * IN;
  float*       op    = out + (size_t)b * H + jw;

  float xa[PF * 3];
  float xb[PF * 3];

  auto loadblk = [&](float* dst, int blk) {
    const float* p = xbase + (size_t)blk * PF * B * IN;
#pragma unroll
    for (int u = 0; u < PF; ++u) {
      dst[u * 3 + 0] = p[(size_t)u * B * IN + 0];
      dst[u * 3 + 1] = p[(size_t)u * B * IN + 1];
      dst[u * 3 + 2] = p[(size_t)u * B * IN + 2];
    }
  };

  auto compute = [&](const float* xv) {
#pragma unroll
    for (int u = 0; u < PF; ++u) {
      // input projection — independent of h, schedules ahead of the chain
      float xp = fmaf(wi0, xv[u * 3 + 0],
                 fmaf(wi1, xv[u * 3 + 1],
                 fmaf(wi2, xv[u * 3 + 2], bb)));

      // 3-stage DPP butterfly all-gather of h across the 8-lane group
      float r1 = dpp_mov<DPP_QUAD_XOR1>(h);    // h[i^1]
      float r2 = dpp_mov<DPP_QUAD_XOR2>(h);    // h[i^2]
      float r3 = dpp_mov<DPP_QUAD_XOR2>(r1);   // h[i^3]
      float r4 = dpp_mov<DPP_ROW_HMIRR>(h);    // h[i^7]
      float r5 = dpp_mov<DPP_ROW_HMIRR>(r1);   // h[i^6]
      float r6 = dpp_mov<DPP_ROW_HMIRR>(r2);   // h[i^5]
      float r7 = dpp_mov<DPP_ROW_HMIRR>(r3);   // h[i^4]

      // two balanced FMA chains over the butterfly slots
      float a1 = fmaf(wh[0], h,
                 fmaf(wh[1], r1,
                 fmaf(wh[2], r2,
                 fmaf(wh[3], r3, xp))));
      float a2 = fmaf(wh[4], r4,
                 fmaf(wh[5], r5,
                 fmaf(wh[6], r6, wh[7] * r7)));
      float a = a1 + a2;

      // tanh(a/c) = 1 - 2/(1 + exp2(a))
      float t = fast_exp2(a);
      h = fmaf(-2.0f, fast_rcp(1.0f + t), 1.0f);

      op[(size_t)u * B * H] = h;
    }
    op += (size_t)PF * B * H;
  };

  loadblk(xa, 0);
  for (int blk = 0; blk < NBLK; blk += 2) {
    loadblk(xb, blk + 1);          // in flight while computing xa's block
    compute(xa);
    if (blk + 2 < NBLK) loadblk(xa, blk + 2);
    compute(xb);
  }

  // h_n tail
  out[(size_t)S * B * H + b * H + jw] = h;
}

extern "C" void kernel_launch(void* const* d_in, const int* in_sizes, int n_in,
                              void* d_out, int out_size, void* d_ws, size_t ws_size,
                              hipStream_t stream) {
  const float* x   = (const float*)d_in[0];
  const float* h0  = (const float*)d_in[1];
  const float* Wih = (const float*)d_in[2];
  const float* Whh = (const float*)d_in[3];
  const float* bih = (const float*)d_in[4];
  const float* bhh = (const float*)d_in[5];
  float* out = (float*)d_out;

  // 4096 batch elements * 8 lanes = 32768 threads = 512 blocks of 64
  // (1 wave per block -> blocks spread across SIMDs; we are chain-latency
  //  bound, so we want waves NOT sharing issue ports).
  dim3 grid((B * 8) / 64), block(64);
  rnn_scan_kernel<<<grid, block, 0, stream>>>(x, h0, Wih, Whh, bih, bhh, out);
}